// Round 27
// baseline (273.122 us; speedup 1.0000x reference)
//
#include <hip/hip_runtime.h>

typedef _Float16 f16;
typedef _Float16 f16x4 __attribute__((ext_vector_type(4)));
typedef _Float16 f16x8 __attribute__((ext_vector_type(8)));
typedef float f32x4 __attribute__((ext_vector_type(4)));
typedef float float4v __attribute__((ext_vector_type(4)));

#define MFMA16(a, b, c) __builtin_amdgcn_mfma_f32_16x16x32_f16(a, b, c, 0, 0, 0)

// ---------------- prep: transpose-cast weights to f16 ----------------
__global__ void k_tr(const float* __restrict__ W, f16* __restrict__ Wt,
                     int K, int N, int lgKp) {
  int t = blockIdx.x * 256 + threadIdx.x;
  int n = t >> lgKp, k = t & ((1 << lgKp) - 1);
  float v = (k < K && n < N) ? W[k * N + n] : 0.f;
  Wt[t] = (f16)v;
}

// ---------------- shared GEMM pieces ----------------

template <int KSTEPS, int NT, int SBIN>
__device__ __forceinline__ void layer8(const char* sm, int inOff,
                                       const f16* __restrict__ wt, int ldw,
                                       int nbase, int kbase, int lr, int ls,
                                       f32x4 (&acc)[NT][8]) {
  const int xr = (lr & 7) << 4;
  const char* pb = sm + inOff + lr * SBIN;
  const f16* wb = wt + (size_t)(nbase + lr) * ldw + kbase + ls * 8;
#pragma unroll
  for (int ks = 0; ks < KSTEPS; ++ks) {
    int cb = (ks * 64 + ls * 16) ^ xr;
    f16x8 b[NT];
#pragma unroll
    for (int nt = 0; nt < NT; ++nt)
      b[nt] = *(const f16x8*)(wb + nt * 16 * ldw + ks * 32);
#pragma unroll
    for (int mh = 0; mh < 2; ++mh) {
      f16x8 a[4];
#pragma unroll
      for (int q = 0; q < 4; ++q)
        a[q] = *(const f16x8*)(pb + (mh * 4 + q) * 16 * SBIN + cb);
#pragma unroll
      for (int nt = 0; nt < NT; ++nt)
#pragma unroll
        for (int q = 0; q < 4; ++q)
          acc[nt][mh * 4 + q] = MFMA16(b[nt], a[q], acc[nt][mh * 4 + q]);
    }
  }
}

template <int NT>
__device__ __forceinline__ void epi8(char* sm, int outOff, int sbout,
                                     const float* __restrict__ bias, int nbias,
                                     int colbase, int lr, int ls,
                                     f32x4 (&acc)[NT][8]) {
  const int xr = (lr & 7) << 4;
#pragma unroll
  for (int nt = 0; nt < NT; ++nt) {
    int n0 = nt * 16 + ls * 4;
    float4v b4 = *(const float4v*)(bias + nbias + n0);
    int cb = ((colbase + n0) * 2) ^ xr;
#pragma unroll
    for (int m = 0; m < 8; ++m) {
      f16x4 h;
#pragma unroll
      for (int r = 0; r < 4; ++r)
        h[r] = (f16)fmaxf(acc[nt][m][r] + b4[r], 0.f);
      *(f16x4*)(sm + outOff + (m * 16 + lr) * sbout + cb) = h;
    }
  }
}

// stage x = concat(obs,act,pad)[128][64] f16 into LDS @xoff (swizzled)
__device__ __forceinline__ void stage_x(char* sm, int xoff, int tid, int r0,
                                        const float* __restrict__ obs,
                                        const float* __restrict__ act) {
#pragma unroll
  for (int half = 0; half < 2; ++half) {
    int a = tid + half * 512;
    int row = a >> 3, g = a & 7;
    const float* ob = obs + (size_t)(r0 + row) * 48;
    const float* ac = act + (size_t)(r0 + row) * 12;
    float f[8];
    if (g < 6) {
#pragma unroll
      for (int i = 0; i < 8; ++i) f[i] = ob[g * 8 + i];
    } else if (g == 6) {
#pragma unroll
      for (int i = 0; i < 8; ++i) f[i] = ac[i];
    } else {
#pragma unroll
      for (int i = 0; i < 8; ++i) f[i] = (i < 4) ? ac[8 + i] : 0.f;
    }
    f16x8 h;
#pragma unroll
    for (int i = 0; i < 8; ++i) h[i] = (f16)f[i];
    *(f16x8*)(sm + xoff + row * 128 + ((g * 16) ^ ((row & 7) << 4))) = h;
  }
}

// ================= SPLIT PATH =================
// k1: layers 1+2 -> h1 global [B][512] f16. LDS 48K -> 3 blocks/CU.
// Panels of 128 h0-cols (each wave builds 16 cols), PAN stride 256.
__global__ __launch_bounds__(512, 2) void k1_l12(
    const float* __restrict__ obs, const float* __restrict__ act,
    const f16* __restrict__ w0t, const f16* __restrict__ w1t,
    const float* __restrict__ b0p, const float* __restrict__ b1p,
    f16* __restrict__ h1g) {
  __shared__ __align__(16) char sm[49152];  // PAN @0 (32K), x @32768 (16K)
  const int tid = threadIdx.x;
  const int wv = tid >> 6, l = tid & 63;
  const int lr = l & 15, ls = l >> 4;
  const int r0 = blockIdx.x * 128;
  const int xr = (lr & 7) << 4;

  stage_x(sm, 32768, tid, r0, obs, act);
  __syncthreads();

  for (int nh = 0; nh < 2; ++nh) {
    f32x4 acc2[2][8];
#pragma unroll
    for (int nt = 0; nt < 2; ++nt)
#pragma unroll
      for (int m = 0; m < 8; ++m) acc2[nt][m] = (f32x4){0.f, 0.f, 0.f, 0.f};

    for (int p = 0; p < 8; ++p) {
      // build panel: h0 cols [p*128,(p+1)*128), wave cols wv*16..wv*16+15
      {
        int n0g = p * 128 + wv * 16;
        const f16* b0 = w0t + (size_t)(n0g + lr) * 64 + ls * 8;
        f16x8 bf0 = *(const f16x8*)(b0);
        f16x8 bf1 = *(const f16x8*)(b0 + 32);
        float4v b4 = *(const float4v*)(b0p + n0g + ls * 4);
        int cb = ((wv * 16 + ls * 4) * 2) ^ xr;
#pragma unroll
        for (int m = 0; m < 8; ++m) {
          const char* px = sm + 32768 + (m * 16 + lr) * 128;
          f16x8 a0 = *(const f16x8*)(px + ((ls * 16) ^ xr));
          f16x8 a1 = *(const f16x8*)(px + ((64 + ls * 16) ^ xr));
          f32x4 c = {0.f, 0.f, 0.f, 0.f};
          c = MFMA16(bf0, a0, c);
          c = MFMA16(bf1, a1, c);
          f16x4 h;
#pragma unroll
          for (int r = 0; r < 4; ++r) h[r] = (f16)fmaxf(c[r] + b4[r], 0.f);
          *(f16x4*)(sm + (m * 16 + lr) * 256 + cb) = h;
        }
      }
      __syncthreads();
      layer8<4, 2, 256>(sm, 0, w1t, 1024, nh * 256 + wv * 32, p * 128,
                        lr, ls, acc2);
      __syncthreads();
    }
    // epilogue: bias+relu -> f16x4 to global h1 (plain [row][512] layout)
#pragma unroll
    for (int nt = 0; nt < 2; ++nt) {
      int n0 = nh * 256 + wv * 32 + nt * 16 + ls * 4;
      float4v b4 = *(const float4v*)(b1p + n0);
#pragma unroll
      for (int m = 0; m < 8; ++m) {
        f16x4 h;
#pragma unroll
        for (int r = 0; r < 4; ++r)
          h[r] = (f16)fmaxf(acc2[nt][m][r] + b4[r], 0.f);
        *(f16x4*)(h1g + (size_t)(r0 + m * 16 + lr) * 512 + n0) = h;
      }
    }
  }
}

// k2: layers 3+4 + softmax + C51. LDS 64K (single buf, overlaid) -> 2/CU.
__global__ __launch_bounds__(512, 2) void k2_l34(
    const f16* __restrict__ h1g, const f16* __restrict__ w2t,
    const f16* __restrict__ w3t, const float* __restrict__ b2p,
    const float* __restrict__ b3p, const float* __restrict__ rew,
    const float* __restrict__ boot, const float* __restrict__ disc,
    const float* __restrict__ qsup, float* __restrict__ out) {
  __shared__ __align__(16) char sm[65536];
  const int tid = threadIdx.x;
  const int wv = tid >> 6, l = tid & 63;
  const int lr = l & 15, ls = l >> 4;
  const int r0 = blockIdx.x * 128;

  // ---- layer 3: stage h1 halves from global, K-split consume ----
  f32x4 acc3[2][8];
#pragma unroll
  for (int nt = 0; nt < 2; ++nt)
#pragma unroll
    for (int m = 0; m < 8; ++m) acc3[nt][m] = (f32x4){0.f, 0.f, 0.f, 0.f};

  for (int half = 0; half < 2; ++half) {
#pragma unroll
    for (int i = 0; i < 8; ++i) {
      int slot = tid + i * 512;        // 4096 slots = row*32 + colgroup
      int row = slot >> 5, cg = slot & 31;
      f16x8 v = *(const f16x8*)(h1g + (size_t)(r0 + row) * 512 +
                                half * 256 + cg * 8);
      *(f16x8*)(sm + row * 512 + ((cg * 16) ^ ((row & 7) << 4))) = v;
    }
    __syncthreads();
    layer8<8, 2, 512>(sm, 0, w2t, 512, wv * 32, half * 256, lr, ls, acc3);
    __syncthreads();  // buf reused (next half / h2)
  }
  epi8<2>(sm, 0, 512, b2p, wv * 32, wv * 32, lr, ls, acc3);  // h2 -> buf
  __syncthreads();

  // ---- layer 4 -> logits (registers), then logits -> buf (h2 dead) ----
  f32x4 acc4[1][8];
#pragma unroll
  for (int m = 0; m < 8; ++m) acc4[0][m] = (f32x4){0.f, 0.f, 0.f, 0.f};
  if (wv < 7)
    layer8<8, 1, 512>(sm, 0, w3t, 256, wv * 16, 0, lr, ls, acc4);
  __syncthreads();  // all h2 reads done
  if (wv < 7) {
    int n0 = wv * 16 + ls * 4;
    float bv[4];
#pragma unroll
    for (int r = 0; r < 4; ++r) bv[r] = (n0 + r < 101) ? b3p[n0 + r] : 0.f;
    float* Lg = (float*)sm;
#pragma unroll
    for (int m = 0; m < 8; ++m) {
      float4v v;
#pragma unroll
      for (int r = 0; r < 4; ++r) v[r] = acc4[0][m][r] + bv[r];
      *(float4v*)(Lg + (m * 16 + lr) * 112 + n0) = v;
    }
  }
  __syncthreads();

  // ---- softmax + projection; lv in registers, Pr overlays logits ----
  int r = tid >> 2, s = tid & 3;
  int rg = r0 + r;
  float lv[26];
  {
    const float* Lg = (const float*)sm;
    float mx = -3.4e38f;
#pragma unroll
    for (int i = 0; i < 26; ++i) {
      int j = s + 4 * i;
      float x = (j < 101) ? Lg[r * 112 + j] : -3.4e38f;
      lv[i] = x;
      mx = fmaxf(mx, x);
    }
    mx = fmaxf(mx, __shfl_xor(mx, 1));
    mx = fmaxf(mx, __shfl_xor(mx, 2));
    float smv = 0.f;
#pragma unroll
    for (int i = 0; i < 26; ++i) {
      float e = expf(lv[i] - mx);
      lv[i] = e;
      if (s + 4 * i < 101) smv += e;
    }
    smv += __shfl_xor(smv, 1);
    smv += __shfl_xor(smv, 2);
#pragma unroll
    for (int i = 0; i < 26; ++i) lv[i] = __fdiv_rn(lv[i], smv);
  }
  __syncthreads();  // all logits consumed into lv
  for (int i = tid; i < 128 * 104 / 4; i += 512)
    ((float4v*)sm)[i] = (float4v){0.f, 0.f, 0.f, 0.f};
  __syncthreads();
  {
    float* Pr = (float*)sm;
    float rw = rew[rg];
    float bd = __fmul_rn(boot[rg], disc[rg]);
#pragma unroll
    for (int i = 0; i < 26; ++i) {
      int j = s + 4 * i;
      if (j < 101) {
        float p = lv[i];
        float tz = __fadd_rn(rw, __fmul_rn(bd, qsup[j]));
        tz = fminf(fmaxf(tz, -10.f), 10.f);
        float bb = __fmul_rn(__fsub_rn(tz, -10.f), 5.0f);
        float fl = floorf(bb), cu = ceilf(bb);
        int li = (int)fl, ui = (int)cu;
        int l2 = li, u2 = ui;
        if (li == ui) {
          if (ui > 0) l2 = li - 1;
          if (li < 100) u2 = ui + 1;
        }
        atomicAdd(&Pr[r * 104 + l2], __fmul_rn(p, __fsub_rn((float)u2, bb)));
        atomicAdd(&Pr[r * 104 + u2], __fmul_rn(p, __fsub_rn(bb, (float)l2)));
      }
    }
  }
  __syncthreads();
  for (int i = tid; i < 128 * 101; i += 512) {
    int rr = i / 101, j = i - rr * 101;
    out[(size_t)(r0 + rr) * 101 + j] = ((const float*)sm)[rr * 104 + j];
  }
}

// ---------------- launch ----------------

extern "C" void kernel_launch(void* const* d_in, const int* in_sizes, int n_in,
                              void* d_out, int out_size, void* d_ws, size_t ws_size,
                              hipStream_t stream) {
  const float* obs  = (const float*)d_in[0];
  const float* act  = (const float*)d_in[1];
  const float* rew  = (const float*)d_in[2];
  const float* boot = (const float*)d_in[3];
  const float* disc = (const float*)d_in[4];
  const float* qsup = (const float*)d_in[5];
  const float* W0 = (const float*)d_in[6];  const float* b0 = (const float*)d_in[7];
  const float* W1 = (const float*)d_in[8];  const float* b1 = (const float*)d_in[9];
  const float* W2 = (const float*)d_in[10]; const float* b2 = (const float*)d_in[11];
  const float* W3 = (const float*)d_in[12]; const float* b3 = (const float*)d_in[13];

  char* ws = (char*)d_ws;
  f16* w0t = (f16*)(ws);             // [1024][64]  131072 B
  f16* w1t = (f16*)(ws + 131072);    // [512][1024] 1048576 B
  f16* w2t = (f16*)(ws + 1179648);   // [256][512]  262144 B
  f16* w3t = (f16*)(ws + 1441792);   // [112][256]  57344 B  (end 1499136)

  k_tr<<<256, 256, 0, stream>>>(W0, w0t, 60, 1024, 6);
  k_tr<<<2048, 256, 0, stream>>>(W1, w1t, 1024, 512, 10);
  k_tr<<<512, 256, 0, stream>>>(W2, w2t, 512, 256, 9);
  k_tr<<<112, 256, 0, stream>>>(W3, w3t, 256, 101, 8);

  const size_t H1_OFF = 1572864;                         // 1.5 MB aligned
  f16* h1g = (f16*)(ws + H1_OFF);                        // 64 MB (ws is ample)
  k1_l12<<<512, 512, 0, stream>>>(obs, act, w0t, w1t, b0, b1, h1g);
  k2_l34<<<512, 512, 0, stream>>>(h1g, w2t, w3t, b2, b3,
                                  rew, boot, disc, qsup, (float*)d_out);
}

// Round 28
// 231.507 us; speedup vs baseline: 1.1798x; 1.1798x over previous
//
#include <hip/hip_runtime.h>

typedef _Float16 f16;
typedef _Float16 f16x4 __attribute__((ext_vector_type(4)));
typedef _Float16 f16x8 __attribute__((ext_vector_type(8)));
typedef float f32x4 __attribute__((ext_vector_type(4)));
typedef float float4v __attribute__((ext_vector_type(4)));

// swapped-operand MFMA: D = Wfrag * Xfrag -> lane holds 4 consecutive n
#define MFMA16(a, b, c) __builtin_amdgcn_mfma_f32_16x16x32_f16(a, b, c, 0, 0, 0)

// M=128 per block, 512 threads (8 waves), 512 blocks.
#define PAN 0
#define H1A 65536
#define XOFF 131072
#define H1B 0
#define H2O 65536
#define LGO 0
#define PRO 65536
#define SMEM_BYTES 147456

// ---------------- prep: transpose-cast weights to f16 ----------------
__global__ void k_tr(const float* __restrict__ W, f16* __restrict__ Wt,
                     int K, int N, int lgKp) {
  int t = blockIdx.x * 256 + threadIdx.x;
  int n = t >> lgKp, k = t & ((1 << lgKp) - 1);
  float v = (k < K && n < N) ? W[k * N + n] : 0.f;
  Wt[t] = (f16)v;
}

// ---------------- fused MLP (f16, M=128) + C51 projection ----------------

template <int KSTEPS, int NT, int SBIN>
__device__ __forceinline__ void layer8(const char* sm, int inOff,
                                       const f16* __restrict__ wt, int ldw,
                                       int nbase, int kbase, int lr, int ls,
                                       f32x4 (&acc)[NT][8]) {
  const int xr = (lr & 7) << 4;
  const char* pb = sm + inOff + lr * SBIN;
  const f16* wb = wt + (size_t)(nbase + lr) * ldw + kbase + ls * 8;
#pragma unroll
  for (int ks = 0; ks < KSTEPS; ++ks) {
    int cb = (ks * 64 + ls * 16) ^ xr;
    f16x8 b[NT];
#pragma unroll
    for (int nt = 0; nt < NT; ++nt)
      b[nt] = *(const f16x8*)(wb + nt * 16 * ldw + ks * 32);
#pragma unroll
    for (int mh = 0; mh < 2; ++mh) {
      f16x8 a[4];
#pragma unroll
      for (int q = 0; q < 4; ++q)
        a[q] = *(const f16x8*)(pb + (mh * 4 + q) * 16 * SBIN + cb);
#pragma unroll
      for (int nt = 0; nt < NT; ++nt)
#pragma unroll
        for (int q = 0; q < 4; ++q)
          acc[nt][mh * 4 + q] = MFMA16(b[nt], a[q], acc[nt][mh * 4 + q]);
    }
  }
}

template <int NT>
__device__ __forceinline__ void epi8(char* sm, int outOff, int sbout,
                                     const float* __restrict__ bias, int nbias,
                                     int colbase, int lr, int ls,
                                     f32x4 (&acc)[NT][8]) {
  const int xr = (lr & 7) << 4;
#pragma unroll
  for (int nt = 0; nt < NT; ++nt) {
    int n0 = nt * 16 + ls * 4;
    float4v b4 = *(const float4v*)(bias + nbias + n0);
    int cb = ((colbase + n0) * 2) ^ xr;
#pragma unroll
    for (int m = 0; m < 8; ++m) {
      f16x4 h;
#pragma unroll
      for (int r = 0; r < 4; ++r)
        h[r] = (f16)fmaxf(acc[nt][m][r] + b4[r], 0.f);
      *(f16x4*)(sm + outOff + (m * 16 + lr) * sbout + cb) = h;
    }
  }
}

__global__ __launch_bounds__(512, 2) void k_fused(
    const float* __restrict__ obs, const float* __restrict__ act,
    const f16* __restrict__ w0t, const f16* __restrict__ w1t,
    const f16* __restrict__ w2t, const f16* __restrict__ w3t,
    const float* __restrict__ b0p, const float* __restrict__ b1p,
    const float* __restrict__ b2p, const float* __restrict__ b3p,
    const float* __restrict__ rew, const float* __restrict__ boot,
    const float* __restrict__ disc, const float* __restrict__ qsup,
    float* __restrict__ out) {
  __shared__ __align__(16) char sm[SMEM_BYTES];
  const int tid = threadIdx.x;
  const int wv = tid >> 6, l = tid & 63;
  const int lr = l & 15, ls = l >> 4;
  const int r0 = blockIdx.x * 128;
  const int xr = (lr & 7) << 4;

  // ---- stage x = concat(obs,act,pad)[128][64] f16 into LDS (swizzled) ----
#pragma unroll
  for (int half = 0; half < 2; ++half) {
    int a = tid + half * 512;
    int row = a >> 3, g = a & 7;
    const float* ob = obs + (size_t)(r0 + row) * 48;
    const float* ac = act + (size_t)(r0 + row) * 12;
    float f[8];
    if (g < 6) {
#pragma unroll
      for (int i = 0; i < 8; ++i) f[i] = ob[g * 8 + i];
    } else if (g == 6) {
#pragma unroll
      for (int i = 0; i < 8; ++i) f[i] = ac[i];
    } else {
#pragma unroll
      for (int i = 0; i < 8; ++i) f[i] = (i < 4) ? ac[8 + i] : 0.f;
    }
    f16x8 h;
#pragma unroll
    for (int i = 0; i < 8; ++i) h[i] = (f16)f[i];
    *(f16x8*)(sm + XOFF + row * 128 + ((g * 16) ^ ((row & 7) << 4))) = h;
  }
  __syncthreads();

  // layer-1 panel builder: h0 cols [p*256,(p+1)*256) -> PAN (stride 512).
  auto layer1_panel = [&](int p) {
#pragma unroll
    for (int nt = 0; nt < 2; ++nt) {
      int n0g = p * 256 + wv * 32 + nt * 16;
      const f16* b0 = w0t + (size_t)(n0g + lr) * 64 + ls * 8;
      f16x8 bf0 = *(const f16x8*)(b0);
      f16x8 bf1 = *(const f16x8*)(b0 + 32);
      float4v b4 = *(const float4v*)(b0p + p * 256 + wv * 32 + nt * 16 + ls * 4);
      int cb = ((wv * 32 + nt * 16 + ls * 4) * 2) ^ xr;
#pragma unroll
      for (int m = 0; m < 8; ++m) {
        const char* px = sm + XOFF + (m * 16 + lr) * 128;
        f16x8 a0 = *(const f16x8*)(px + ((ls * 16) ^ xr));
        f16x8 a1 = *(const f16x8*)(px + ((64 + ls * 16) ^ xr));
        f32x4 c = {0.f, 0.f, 0.f, 0.f};
        c = MFMA16(bf0, a0, c);
        c = MFMA16(bf1, a1, c);
        f16x4 h;
#pragma unroll
        for (int r = 0; r < 4; ++r) h[r] = (f16)fmaxf(c[r] + b4[r], 0.f);
        *(f16x4*)(sm + PAN + (m * 16 + lr) * 512 + cb) = h;
      }
    }
  };

  // ---- layers 1+2: two N-halves of 256, each over 4 K-panels ----
  for (int nh = 0; nh < 2; ++nh) {
    f32x4 acc2[2][8];
#pragma unroll
    for (int nt = 0; nt < 2; ++nt)
#pragma unroll
      for (int m = 0; m < 8; ++m) acc2[nt][m] = (f32x4){0.f, 0.f, 0.f, 0.f};

    for (int p = 0; p < 4; ++p) {
      layer1_panel(p);
      __syncthreads();
      layer8<8, 2, 512>(sm, PAN, w1t, 1024, nh * 256 + wv * 32, p * 256,
                        lr, ls, acc2);
      __syncthreads();
    }
    epi8<2>(sm, nh == 0 ? H1A : H1B, 512, b1p, nh * 256 + wv * 32, wv * 32,
            lr, ls, acc2);
    __syncthreads();
  }

  // ---- layer 3: K=512 via two h1 halves, N=256 ----
  f32x4 acc3[2][8];
#pragma unroll
  for (int nt = 0; nt < 2; ++nt)
#pragma unroll
    for (int m = 0; m < 8; ++m) acc3[nt][m] = (f32x4){0.f, 0.f, 0.f, 0.f};
  layer8<8, 2, 512>(sm, H1A, w2t, 512, wv * 32, 0, lr, ls, acc3);
  layer8<8, 2, 512>(sm, H1B, w2t, 512, wv * 32, 256, lr, ls, acc3);
  __syncthreads();
  epi8<2>(sm, H2O, 512, b2p, wv * 32, wv * 32, lr, ls, acc3);
  __syncthreads();

  // ---- layer 4: K=256, N=112 (waves 0..6) -> logits f32 @LGO ----
  if (wv < 7) {
    f32x4 acc4[1][8];
#pragma unroll
    for (int m = 0; m < 8; ++m) acc4[0][m] = (f32x4){0.f, 0.f, 0.f, 0.f};
    layer8<8, 1, 512>(sm, H2O, w3t, 256, wv * 16, 0, lr, ls, acc4);
    int n0 = wv * 16 + ls * 4;  // 4 consecutive logit cols per lane
    float bv[4];
#pragma unroll
    for (int r = 0; r < 4; ++r) bv[r] = (n0 + r < 101) ? b3p[n0 + r] : 0.f;
    float* Lg = (float*)(sm + LGO);
#pragma unroll
    for (int m = 0; m < 8; ++m) {
      int row = m * 16 + lr;
      float4v v;
#pragma unroll
      for (int r = 0; r < 4; ++r) v[r] = acc4[0][m][r] + bv[r];
      *(float4v*)(Lg + row * 112 + n0) = v;
    }
  }
  __syncthreads();

  // zero projection bins (over dead h2), float4
  for (int i = tid; i < 128 * 104 / 4; i += 512)
    ((float4v*)(sm + PRO))[i] = (float4v){0.f, 0.f, 0.f, 0.f};
  __syncthreads();

  // ---- softmax (f32) + C51 projection; 4 threads per batch row ----
  {
    int r = tid >> 2, s = tid & 3;
    int rg = r0 + r;
    const float* Lg = (const float*)(sm + LGO);
    float* Pr = (float*)(sm + PRO);
    float lv[26];
    float mx = -3.4e38f;
#pragma unroll
    for (int i = 0; i < 26; ++i) {
      int j = s + 4 * i;
      float x = (j < 101) ? Lg[r * 112 + j] : -3.4e38f;
      lv[i] = x;
      mx = fmaxf(mx, x);
    }
    mx = fmaxf(mx, __shfl_xor(mx, 1));
    mx = fmaxf(mx, __shfl_xor(mx, 2));
    float smv = 0.f;
#pragma unroll
    for (int i = 0; i < 26; ++i) {
      float e = expf(lv[i] - mx);
      lv[i] = e;
      if (s + 4 * i < 101) smv += e;
    }
    smv += __shfl_xor(smv, 1);
    smv += __shfl_xor(smv, 2);

    // Verified-match chain (R8): tz = rew + (boot*disc)*q, clip,
    // b = (tz - V_MIN) * 5.0f   [1/delta_z == 5.0 exactly]
    float rw = rew[rg];
    float bd = __fmul_rn(boot[rg], disc[rg]);
#pragma unroll
    for (int i = 0; i < 26; ++i) {
      int j = s + 4 * i;
      if (j < 101) {
        float p = __fdiv_rn(lv[i], smv);
        float tz = __fadd_rn(rw, __fmul_rn(bd, qsup[j]));
        tz = fminf(fmaxf(tz, -10.f), 10.f);
        float bb = __fmul_rn(__fsub_rn(tz, -10.f), 5.0f);
        float fl = floorf(bb), cu = ceilf(bb);
        int li = (int)fl, ui = (int)cu;
        int l2 = li, u2 = ui;
        if (li == ui) {
          if (ui > 0) l2 = li - 1;
          if (li < 100) u2 = ui + 1;
        }
        atomicAdd(&Pr[r * 104 + l2], __fmul_rn(p, __fsub_rn((float)u2, bb)));
        atomicAdd(&Pr[r * 104 + u2], __fmul_rn(p, __fsub_rn(bb, (float)l2)));
      }
    }
  }
  __syncthreads();

  for (int i = tid; i < 128 * 101; i += 512) {
    int r = i / 101, j = i - r * 101;
    out[(size_t)(r0 + r) * 101 + j] = ((const float*)(sm + PRO))[r * 104 + j];
  }
}

// ---------------- launch ----------------

extern "C" void kernel_launch(void* const* d_in, const int* in_sizes, int n_in,
                              void* d_out, int out_size, void* d_ws, size_t ws_size,
                              hipStream_t stream) {
  const float* obs  = (const float*)d_in[0];
  const float* act  = (const float*)d_in[1];
  const float* rew  = (const float*)d_in[2];
  const float* boot = (const float*)d_in[3];
  const float* disc = (const float*)d_in[4];
  const float* qsup = (const float*)d_in[5];
  const float* W0 = (const float*)d_in[6];  const float* b0 = (const float*)d_in[7];
  const float* W1 = (const float*)d_in[8];  const float* b1 = (const float*)d_in[9];
  const float* W2 = (const float*)d_in[10]; const float* b2 = (const float*)d_in[11];
  const float* W3 = (const float*)d_in[12]; const float* b3 = (const float*)d_in[13];

  char* ws = (char*)d_ws;
  f16* w0t = (f16*)(ws);             // [1024][64]  131072 B
  f16* w1t = (f16*)(ws + 131072);    // [512][1024] 1048576 B
  f16* w2t = (f16*)(ws + 1179648);   // [256][512]  262144 B
  f16* w3t = (f16*)(ws + 1441792);   // [112][256]  57344 B  (end 1499136)

  k_tr<<<256, 256, 0, stream>>>(W0, w0t, 60, 1024, 6);
  k_tr<<<2048, 256, 0, stream>>>(W1, w1t, 1024, 512, 10);
  k_tr<<<512, 256, 0, stream>>>(W2, w2t, 512, 256, 9);
  k_tr<<<112, 256, 0, stream>>>(W3, w3t, 256, 101, 8);

  k_fused<<<512, 512, 0, stream>>>(obs, act, w0t, w1t, w2t, w3t,
                                   b0, b1, b2, b3,
                                   rew, boot, disc, qsup, (float*)d_out);
}